// Round 8
// baseline (170.604 us; speedup 1.0000x reference)
//
#include <hip/hip_runtime.h>
#include <hip/hip_fp16.h>

// SSIM loss, fused, async-prefetch rolling-ring, 8-row steps. fp32 in
// [16,3,512,512], fp32 scalar out. Round-7 postmortem: structure works
// (78 us, VALUBusy 60%) but LDS 45.5 KB caps residency at ~2-3 blocks/CU
// -> ~25 us of exposed stall. This round halves the pipeline period:
// 8-row steps shrink the ring span to 26 rows (RING 32 = 16 KB) and the
// raw dbuf to 2x5 KB; total LDS 26.8 KB -> 6 blocks/CU (grid = exactly
// 6/CU), so barrier/latency gaps overlap across blocks.
// Per step: [async global_load_lds prefetch of step j+1's 8 raw rows] ->
// [waves 0-1: hblur 8 rows from raw LDS into ring slots rel 8j+18..25]
// || [all: vblur+SSIM rows rel 8j..8j+7 (reads rel 8j..8j+17, disjoint)]
// -> ONE barrier. fp16 interleaved ring (p,t,p^2+t^2,p*t), fp32 math
// (absmax 0.0 in rounds 3-7); no cross-phase register carry (spill-safe).

#define WIDTH  512
#define HEIGHT 512
#define TW 64
#define SH 128
#define STEP 8
#define NSTEP (SH / STEP)        // 16
#define RING 32
#define ROWB 512                 // ring row stride: 64 cols * 4 halves * 2 B
#define TILES_X 8
#define TILES_Y (HEIGHT / SH)    // 4
#define PLANES 48
#define NBLK (TILES_X * TILES_Y * PLANES)   // 1536
#define NPIXF 12582912.0f

// blur 4 quantities for 4 output cols from 20-float raw windows; pack fp16
// interleaved per-pixel (p,t,u,v) and store 32 B contiguous (2x b128).
__device__ __forceinline__ void hblur_pack_store(const float* __restrict__ w,
                                                 const float* __restrict__ p,
                                                 const float* __restrict__ t,
                                                 __half* __restrict__ dst) {
    float aa[4] = {0,0,0,0}, ab[4] = {0,0,0,0},
          au[4] = {0,0,0,0}, av[4] = {0,0,0,0};
#pragma unroll
    for (int m = 3; m <= 16; ++m) {
        float pm = p[m], tm = t[m];
        float vm = pm * tm;
        float um = fmaf(pm, pm, tm * tm);
#pragma unroll
        for (int k = 0; k < 4; ++k) {
            int i = m - 3 - k;
            if (i >= 0 && i <= 10) {
                float wi = w[i];
                aa[k] = fmaf(wi, pm, aa[k]);
                ab[k] = fmaf(wi, tm, ab[k]);
                au[k] = fmaf(wi, um, au[k]);
                av[k] = fmaf(wi, vm, av[k]);
            }
        }
    }
    union { __half2 h2[8]; uint4 u4[2]; } pk;
#pragma unroll
    for (int k = 0; k < 4; ++k) {
        pk.h2[2*k+0] = __floats2half2_rn(aa[k], ab[k]);
        pk.h2[2*k+1] = __floats2half2_rn(au[k], av[k]);
    }
    ((uint4*)dst)[0] = pk.u4[0];
    ((uint4*)dst)[1] = pk.u4[1];
}

// Prologue path: plain global loads with full masking (handles gy<0).
__device__ __forceinline__ void hblur_row_global(
    const float* __restrict__ P, const float* __restrict__ T,
    int x0, int gy, int cg, bool x_int, const float* __restrict__ w,
    __half* __restrict__ dst) {
    float p[20], t[20];
    if ((unsigned)gy >= (unsigned)HEIGHT) {
#pragma unroll
        for (int i = 0; i < 20; ++i) { p[i] = 0.f; t[i] = 0.f; }
    } else {
        const float* Pr = P + (size_t)gy * WIDTH;
        const float* Tr = T + (size_t)gy * WIDTH;
        const int gx0 = x0 + cg * 4 - 8;
        if (x_int) {
            const float4* Pq = (const float4*)(Pr + gx0);
            const float4* Tq = (const float4*)(Tr + gx0);
#pragma unroll
            for (int v = 0; v < 5; ++v) {
                float4 a = Pq[v], b = Tq[v];
                p[4*v+0] = a.x; p[4*v+1] = a.y; p[4*v+2] = a.z; p[4*v+3] = a.w;
                t[4*v+0] = b.x; t[4*v+1] = b.y; t[4*v+2] = b.z; t[4*v+3] = b.w;
            }
        } else {
#pragma unroll
            for (int i = 0; i < 20; ++i) {
                int gx = gx0 + i;
                bool ok = (unsigned)gx < (unsigned)WIDTH;
                p[i] = ok ? Pr[gx] : 0.f;
                t[i] = ok ? Tr[gx] : 0.f;
            }
        }
    }
    hblur_pack_store(w, p, t, dst);
}

__global__ __launch_bounds__(256)
void ssim_main(const float* __restrict__ pred,
               const float* __restrict__ tgt,
               float* __restrict__ partial) {
    __shared__ __half s_h[RING][TW][4];        // 16384 B ring
    __shared__ float s_raw[2][2][STEP][80];    // 10240 B raw dbuf [buf][arr][row][col]
    __shared__ float s_red[4];

    const int tid = threadIdx.x;
    const int x0 = blockIdx.x * TW;
    const int y0 = blockIdx.y * SH;
    const size_t plane_off = (size_t)blockIdx.z * (WIDTH * HEIGHT);
    const float* P = pred + plane_off;
    const float* T = tgt + plane_off;
    const bool x_int = (x0 >= 8) && (x0 + TW + 8 <= WIDTH);

    const float w[11] = {0.00102839f, 0.00759881f, 0.03600077f, 0.10936069f,
                         0.21300566f, 0.26601168f, 0.21300566f, 0.10936069f,
                         0.03600077f, 0.00759881f, 0.00102839f};

    const int wv   = tid >> 6;         // wave id (uniform per wave)
    const int lane = tid & 63;
    const int r1   = (tid >> 4) & 7;   // phase-1 row 0..7 (tid<128 active)
    const int cg1  = tid & 15;         // phase-1 col-group
    const int c    = tid & 63;         // phase-2 column
    const int rr   = (tid >> 6) << 1;  // phase-2 row offset 0/2/4/6

    // Async raw prefetch: one buffer = 2 arrays x 8 rows x 80 cols fp32
    // = 5120 B = 5 wave-wide 1024-B transfers. LDS dest is wave-uniform
    // base + lane*16 (HW rule); global addrs clamped (consumers mask).
    auto issue_async = [&](int buf, int gybase) {
#pragma unroll 1
        for (int l = wv; l < 5; l += 4) {
            int fi  = l * 256 + lane * 4;        // float idx in 1280-float buf
            int arr = fi / 640;                  // 0=pred, 1=tgt
            int rem = fi - arr * 640;
            int row = rem / 80;
            int col = rem - row * 80;
            int gy = gybase + row; if (gy > HEIGHT - 1) gy = HEIGHT - 1;
            int gx = x0 - 8 + col;
            if (gx < 0) gx = 0;
            if (gx > WIDTH - 4) gx = WIDTH - 4;
            const float* src = (arr == 0 ? P : T) + ((size_t)gy << 9) + gx;
            char* ldsbase = (char*)&s_raw[buf][0][0][0] + l * 1024;
            __builtin_amdgcn_global_load_lds(
                (const __attribute__((address_space(1))) unsigned int*)(const void*)src,
                (__attribute__((address_space(3))) unsigned int*)(void*)ldsbase,
                16, 0, 0);
        }
    };

    // ---- Prologue ----
    issue_async(0, y0 + STEP + 5);              // raw rows for step-0 phase-1
    // Stage ring rel rows 0..17 (gy = y0-5 .. y0+12): 18 x 16 = 288 items.
#pragma unroll 1
    for (int it = tid; it < 18 * 16; it += 256) {
        int r = it >> 4, cg = it & 15;
        hblur_row_global(P, T, x0, y0 - 5 + r, cg, x_int, w, &s_h[r][cg * 4][0]);
    }
    __syncthreads();                            // also drains prologue async

    float lsum = 0.f;

#pragma unroll 1
    for (int j = 0; j < NSTEP; ++j) {
        // ---- A: async raw prefetch for step j+1's phase-1 ----
        if (j < NSTEP - 2) issue_async((j + 1) & 1, y0 + STEP * (j + 1) + 13);

        // ---- B: phase-1 (waves 0-1) — hblur 8 rows from raw LDS ----
        // gy = y0+8j+13+r1 -> ring rel 8j+18+r1 (disjoint from C's reads).
        if (j < NSTEP - 1 && tid < 128) {
            const int gy = y0 + STEP * j + 13 + r1;
            const int buf = j & 1;
            float p[20], t[20];
            const float4* rp = (const float4*)&s_raw[buf][0][r1][cg1 * 4];
            const float4* rt = (const float4*)&s_raw[buf][1][r1][cg1 * 4];
#pragma unroll
            for (int v = 0; v < 5; ++v) {
                float4 a = rp[v], b = rt[v];
                p[4*v+0] = a.x; p[4*v+1] = a.y; p[4*v+2] = a.z; p[4*v+3] = a.w;
                t[4*v+0] = b.x; t[4*v+1] = b.y; t[4*v+2] = b.z; t[4*v+3] = b.w;
            }
            if (!x_int || gy > HEIGHT - 1) {     // edge masking (clamped loads)
                const int gx0 = x0 + cg1 * 4 - 8;
                const bool row_ok = gy <= HEIGHT - 1;
#pragma unroll
                for (int i = 0; i < 20; ++i) {
                    bool ok = row_ok && ((unsigned)(gx0 + i) < (unsigned)WIDTH);
                    if (!ok) { p[i] = 0.f; t[i] = 0.f; }
                }
            }
            const int s = (STEP * j + 18 + r1) & (RING - 1);
            hblur_pack_store(w, p, t, &s_h[s][cg1 * 4][0]);
        }

        // ---- C: phase-2 — vblur + SSIM, 2 rows x 1 col per thread ----
        // Output rows rel 8j+rr, 8j+rr+1; reads ring rel 8j+rr+m, m<12.
        {
            const int s0 = (STEP * j + rr) & (RING - 1);
            const int kwrap = RING - s0;
            const char* base = (const char*)&s_h[0][0][0];
            const int offA = s0 * ROWB + c * 8;
            const int offB = offA - RING * ROWB;

            float a2[2] = {0,0}, b2[2] = {0,0}, u2[2] = {0,0}, v2[2] = {0,0};
#pragma unroll
            for (int m = 0; m < 12; ++m) {
                const uint2 d = *(const uint2*)(base + (m < kwrap ? offA : offB)
                                                + m * ROWB);
                const float2 f0 = __half22float2(__builtin_bit_cast(__half2, d.x));
                const float2 f1 = __half22float2(__builtin_bit_cast(__half2, d.y));
#pragma unroll
                for (int r = 0; r < 2; ++r) {
                    int i = m - r;
                    if (i >= 0 && i <= 10) {
                        float wi = w[i];
                        a2[r] = fmaf(wi, f0.x, a2[r]);
                        b2[r] = fmaf(wi, f0.y, b2[r]);
                        u2[r] = fmaf(wi, f1.x, u2[r]);
                        v2[r] = fmaf(wi, f1.y, v2[r]);
                    }
                }
            }
#pragma unroll
            for (int r = 0; r < 2; ++r) {
                float mp = a2[r], mt = b2[r];
                float mpt = mp * mt;
                float B = fmaf(mp, mp, mt * mt);
                float spt  = v2[r] - mpt;        // sigma_pt
                float ssum = u2[r] - B;          // sigma_p + sigma_t
                float num = (2.f * mpt + 1e-4f) * (2.f * spt + 9e-4f);
                float den = (B + 1e-4f) * (ssum + 9e-4f);
                lsum += __fdividef(num, den);
            }
        }

        __syncthreads();   // single barrier: ring handoff + async drain
    }

    // ---- Block reduction -> one partial per block ----
#pragma unroll
    for (int off = 32; off > 0; off >>= 1) lsum += __shfl_down(lsum, off);
    if ((tid & 63) == 0) s_red[tid >> 6] = lsum;
    __syncthreads();
    if (tid == 0) {
        partial[(blockIdx.z * TILES_Y + blockIdx.y) * TILES_X + blockIdx.x] =
            s_red[0] + s_red[1] + s_red[2] + s_red[3];
    }
}

__global__ __launch_bounds__(256)
void ssim_final(const float* __restrict__ partial, float* __restrict__ out) {
    __shared__ float s_red[4];
    float s = 0.f;
    for (int i = threadIdx.x; i < NBLK; i += 256) s += partial[i];
#pragma unroll
    for (int off = 32; off > 0; off >>= 1) s += __shfl_down(s, off);
    if ((threadIdx.x & 63) == 0) s_red[threadIdx.x >> 6] = s;
    __syncthreads();
    if (threadIdx.x == 0) {
        float total = s_red[0] + s_red[1] + s_red[2] + s_red[3];
        out[0] = 1.0f - total / NPIXF;
    }
}

extern "C" void kernel_launch(void* const* d_in, const int* in_sizes, int n_in,
                              void* d_out, int out_size, void* d_ws, size_t ws_size,
                              hipStream_t stream) {
    const float* pred = (const float*)d_in[0];
    const float* tgt  = (const float*)d_in[1];
    float* partial = (float*)d_ws;   // NBLK floats, fully rewritten each call

    dim3 grid(TILES_X, TILES_Y, PLANES);
    ssim_main<<<grid, dim3(256), 0, stream>>>(pred, tgt, partial);
    ssim_final<<<1, dim3(256), 0, stream>>>(partial, (float*)d_out);
}